// Round 10
// baseline (5600.391 us; speedup 1.0000x reference)
//
#include <hip/hip_runtime.h>
#include <cstdint>

typedef unsigned short u16;
typedef __attribute__((ext_vector_type(4))) float f32x4;
typedef __attribute__((ext_vector_type(8))) short bf16x8;   // 8 bf16 in 4 VGPRs
typedef __attribute__((ext_vector_type(4))) u16 u16x4;

constexpr int NB = 1024;   // batch
constexpr int NT = 200;    // time
constexpr int ND = 128;    // input dim
constexpr int NU = 128;    // units
constexpr int NG = 512;    // 4*U gates
constexpr int ROWS = 8;    // batch rows per block (M=16 MFMA, rows 8-15 zero-pad)
constexpr int NGRP = NB / ROWS;           // 128 groups
constexpr int CHUNK = 8;   // pipeline handshake granularity (divides NT)
constexpr int LDS_A_ELEMS = 16 * 512;     // padded 16-row A tile: 16 KiB

__device__ __forceinline__ u16 f2bf(float x) {
    uint32_t u = __builtin_bit_cast(uint32_t, x);
    u = (u + 0x7fffu + ((u >> 16) & 1u)) >> 16;   // RNE
    return (u16)u;
}
__device__ __forceinline__ float bf2f(u16 b) {
    uint32_t u = ((uint32_t)b) << 16;
    return __builtin_bit_cast(float, u);
}
__device__ __forceinline__ float sigm(float x) {
    return __builtin_amdgcn_rcpf(1.f + __expf(-x));
}
__device__ __forceinline__ float tanh_fast(float x) {
    float e = __expf(-2.f * fabsf(x));
    float t = (1.f - e) * __builtin_amdgcn_rcpf(1.f + e);
    return copysignf(t, x);
}

// Poll RELAXED (no L2 inv), with a PERIODIC acquire (~27 us apart) so progress
// is guaranteed even if producer/consumer land on different XCDs (relaxed
// loads can otherwise spin on a stale local-L2 line forever). One final
// acquire gives the synchronizes-with edge. r8 lesson: acquire EVERY poll
// = whole-L2 buffer_inv storm (+80%/step).
__device__ __forceinline__ void spin_gate(const int* p, int need) {
    int k = 0;
    while (__hip_atomic_load(p, __ATOMIC_RELAXED, __HIP_MEMORY_SCOPE_AGENT) < need) {
        __builtin_amdgcn_s_sleep(16);
        if ((++k & 63) == 0)
            (void)__hip_atomic_load(p, __ATOMIC_ACQUIRE, __HIP_MEMORY_SCOPE_AGENT);
    }
    (void)__hip_atomic_load(p, __ATOMIC_ACQUIRE, __HIP_MEMORY_SCOPE_AGENT);
}

// One LSTM layer scan for 8 batch rows (16-row zero-padded MFMA tile).
// 3 register weight arrays (Wk_hi, Wr_hi, Wr_lo) — exactly 3 fit (r6: a 4th
// forces global rematerialization, FETCH 25x). Wk_lo correction dropped
// (precision ledger: r2 0.0039 full, r3 0.0059 with L0 dropped; predicted
// ~0.006-0.012 with both dropped, threshold 0.0188). Recurrence stays
// protected: A hi+lo, h hi+lo, Wr hi+lo.
template<bool PROD, bool CONS>
__device__ __forceinline__ void run_layer(
    const float* __restrict__ Wk, const float* __restrict__ Wr,
    const float* __restrict__ Bv,
    const float* __restrict__ src, float* __restrict__ dst,
    u16* A, int* prog_c,
    const int dir, const int base_b,
    const int tid, const int q, const int cl, const int uu,
    const int sr, const int sc)
{
    // ---- resident weight fragments (B-side): Wk_hi, Wr_hi, Wr_lo
    bf16x8 wkh[4][4], wrh[4][4], wrl[4][4];
    #pragma unroll
    for (int g = 0; g < 4; ++g) {
        const int col = g * NU + uu;
        #pragma unroll
        for (int s = 0; s < 4; ++s) {
            bf16x8 fa, fh, fl;
            #pragma unroll
            for (int j = 0; j < 8; ++j) {
                const int k = s * 32 + q * 8 + j;
                fa[j] = (short)f2bf(Wk[k * NG + col]);
                const float w = Wr[k * NG + col];
                const u16 hi = f2bf(w);
                fh[j] = (short)hi;
                fl[j] = (short)f2bf(w - bf2f(hi));
            }
            wkh[g][s] = fa; wrh[g][s] = fh; wrl[g][s] = fl;
        }
    }
    float bias[4];
    #pragma unroll
    for (int g = 0; g < 4; ++g) bias[g] = Bv[g * NU + uu];

    for (int i = tid; i < LDS_A_ELEMS; i += 512) A[i] = 0;   // rows 8-15 stay 0
    f32x4 cc = {0.f, 0.f, 0.f, 0.f};

    const size_t srow = (size_t)(base_b + sr) * (NT * NU) + sc;
    const uint32_t stg = (uint32_t)(sr * 1024 + ((2 * sc) ^ ((sr & 7) << 4))) >> 1;

    // pre-loop gate: x_{t(0..8)} needed -> round up to publish grid (16)
    if (CONS && tid == 0) spin_gate(prog_c, (2 * CHUNK < NT) ? 2 * CHUNK : NT);
    __syncthreads();   // zeroing visible; gate result broadcast
    float4 cur;
    if (tid < 256) cur = *(const float4*)&src[srow + (size_t)(dir ? NT - 1 : 0) * NU];

    for (int cs = 0; cs < NT; cs += CHUNK) {
        // gate chunk cs: prefetches x_{cs+1}..x_{cs+8} -> need cs+16 (grid-rounded)
        if (CONS && cs > 0) {
            if (tid == 0) {
                const int need = (cs + 2 * CHUNK < NT) ? cs + 2 * CHUNK : NT;
                spin_gate(prog_c, need);
            }
            __syncthreads();
        }

        for (int step = cs; step < cs + CHUNK; ++step) {
            const int t = dir ? (NT - 1 - step) : step;

            // ---- stage x_t (in regs) as hi+lo into A rows 0-7, k<256
            if (tid < 256) {
                const float vv[4] = {cur.x, cur.y, cur.z, cur.w};
                u16x4 hi4, lo4;
                #pragma unroll
                for (int e = 0; e < 4; ++e) {
                    const u16 h = f2bf(vv[e]);
                    hi4[e] = h;
                    lo4[e] = f2bf(vv[e] - bf2f(h));
                }
                *(u16x4*)&A[stg]       = hi4;   // x_hi: k in [0,128)
                *(u16x4*)&A[stg + 128] = lo4;   // x_lo: k in [128,256)
            }
            __syncthreads();   // sync1: staging visible; all waves' older stores drained

            // publish at chunk boundaries: steps 0..step-1 drained by sync1
            if (PROD && tid == 0 && step && (step & (CHUNK - 1)) == 0)
                __hip_atomic_store(prog_c, step, __ATOMIC_RELEASE, __HIP_MEMORY_SCOPE_AGENT);

            // prefetch x_{t(step+1)} (chunk-gated)
            if (tid < 256 && step + 1 < NT) {
                const int tn = dir ? (NT - 2 - step) : (step + 1);
                cur = *(const float4*)&src[srow + (size_t)tn * NU];
            }

            f32x4 accx[4], acch[4];   // x-side (carries bias) and h-side chains
            #pragma unroll
            for (int g = 0; g < 4; ++g) {
                accx[g] = (f32x4){bias[g], bias[g], bias[g], bias[g]};
                acch[g] = (f32x4){0.f, 0.f, 0.f, 0.f};
            }

            #pragma unroll
            for (int s = 0; s < 4; ++s) {
                const uint32_t ab =
                    (uint32_t)(cl * 1024 + ((s * 64 + q * 16) ^ ((cl & 15) << 4)));
                const bf16x8 axh = *(const bf16x8*)&A[(ab >> 1)];
                const bf16x8 axl = *(const bf16x8*)&A[(ab >> 1) + 128];
                const bf16x8 ahh = *(const bf16x8*)&A[(ab >> 1) + 256];
                const bf16x8 ahl = *(const bf16x8*)&A[(ab >> 1) + 384];
                #pragma unroll
                for (int g = 0; g < 4; ++g) {
                    accx[g] = __builtin_amdgcn_mfma_f32_16x16x32_bf16(axh, wkh[g][s], accx[g], 0, 0, 0);
                    accx[g] = __builtin_amdgcn_mfma_f32_16x16x32_bf16(axl, wkh[g][s], accx[g], 0, 0, 0);
                    acch[g] = __builtin_amdgcn_mfma_f32_16x16x32_bf16(ahh, wrh[g][s], acch[g], 0, 0, 0);
                    acch[g] = __builtin_amdgcn_mfma_f32_16x16x32_bf16(ahl, wrh[g][s], acch[g], 0, 0, 0);
                    acch[g] = __builtin_amdgcn_mfma_f32_16x16x32_bf16(ahh, wrl[g][s], acch[g], 0, 0, 0);
                }
            }
            __syncthreads();   // sync2: frag reads done before h region is overwritten

            // gates + state; C/D: col = lane&15 (unit), row = q*4+j (batch row).
            // Only rows < 8 are real (q<2); rows 8-15 are the zero-pad.
            #pragma unroll
            for (int j = 0; j < 4; ++j) {
                const int r = q * 4 + j;
                const float gi = sigm(accx[0][j] + acch[0][j]);
                const float gf = sigm(accx[1][j] + acch[1][j]);
                const float gg = tanh_fast(accx[2][j] + acch[2][j]);
                const float go = sigm(accx[3][j] + acch[3][j]);
                const float cn = gf * cc[j] + gi * gg;
                cc[j] = cn;
                const float h = go * tanh_fast(cn);
                if (r < ROWS) {
                    const u16 hh = f2bf(h);
                    const u16 hl = f2bf(h - bf2f(hh));
                    const uint32_t hb = (uint32_t)(r * 1024 + ((2 * uu) ^ ((r & 15) << 4)));
                    A[(hb >> 1) + 256] = hh;   // h_hi: k in [256,384)
                    A[(hb >> 1) + 384] = hl;   // h_lo: k in [384,512)
                    dst[(size_t)(base_b + r) * (NT * NU) + (size_t)t * NU + uu] = h;
                }
            }
            // next step's sync1 orders these h writes vs reads, drains dst stores
        }
    }

    __syncthreads();   // drain final step's dst stores
    if (PROD && tid == 0)
        __hip_atomic_store(prog_c, NT, __ATOMIC_RELEASE, __HIP_MEMORY_SCOPE_AGENT);
}

// grid = (128 groups, 2 dirs, 2 layers) = 512 blocks, 16 KiB LDS each ->
// 2 blocks/CU co-resident: one block's barrier stalls hide under the other's
// compute (the r2-r9 invariant: 1 block/CU left ~8k cyc/step unhidable).
// Producer i and consumer i+256 land on the same XCD (256 % 8 == 0).
// If capacity ever drops to 1 block/CU the pipeline degrades to sequential
// but cannot deadlock (producers never wait on consumers).
__global__ __launch_bounds__(512, 4)
void lstm_scan(const float* __restrict__ x,
               const float* __restrict__ fwk, const float* __restrict__ fwrk,
               const float* __restrict__ fwb,
               const float* __restrict__ bwk, const float* __restrict__ bwrk,
               const float* __restrict__ bwb,
               float* __restrict__ buf_fw, float* __restrict__ buf_bw,
               int* __restrict__ prog) {
    __shared__ __align__(16) u16 A[LDS_A_ELEMS];   // [16][512] bf16, swizzled

    const int tid   = threadIdx.x;
    const int lane  = tid & 63;
    const int wv    = tid >> 6;         // wave 0..7
    const int grp   = blockIdx.x;       // 0..127
    const int dir   = blockIdx.y;       // 0 = fw, 1 = bw
    const int layer = blockIdx.z;       // 0 = producer, 1 = consumer
    const int base_b = grp * ROWS;

    const float* kp = dir ? bwk  : fwk;
    const float* rp = dir ? bwrk : fwrk;
    const float* bp = dir ? bwb  : fwb;
    float* buf = dir ? buf_bw : buf_fw;
    int* prog_c = prog + dir * NGRP + grp;

    const int q  = lane >> 4;           // k-group 0..3
    const int cl = lane & 15;           // A-row / B-col within tile
    const int uu = (wv << 4) + cl;      // unit 0..127 owned by this lane

    const int sr = tid >> 5;            // staging row 0..7 (tid < 256)
    const int sc = (tid & 31) << 2;     // staging col 0..124

    if (layer == 0) {
        // layer 0: x -> buf (h0), publishing progress
        run_layer<true, false>(kp, rp, bp, x, buf, A, prog_c,
                               dir, base_b, tid, q, cl, uu, sr, sc);
    } else {
        // layer 1: buf (h0) -> buf in-place (h1), gated on producer progress.
        // In-place safe: h0[t] is last read one step before h1[t] is written.
        run_layer<false, true>(kp + ND * NG, rp + NU * NG, bp + NG,
                               buf, buf, A, prog_c,
                               dir, base_b, tid, q, cl, uu, sr, sc);
    }
}

// ---- merge: out = 0.5*(fw + bw) ---------------------------------------------
__global__ void merge_out(const float* __restrict__ a, const float* __restrict__ b,
                          float* __restrict__ o, int nvec) {
    int i = blockIdx.x * blockDim.x + threadIdx.x;
    const int st = gridDim.x * blockDim.x;
    for (; i < nvec; i += st) {
        const float4 va = ((const float4*)a)[i];
        const float4 vb = ((const float4*)b)[i];
        float4 r;
        r.x = 0.5f * (va.x + vb.x);
        r.y = 0.5f * (va.y + vb.y);
        r.z = 0.5f * (va.z + vb.z);
        r.w = 0.5f * (va.w + vb.w);
        ((float4*)o)[i] = r;
    }
}

extern "C" void kernel_launch(void* const* d_in, const int* in_sizes, int n_in,
                              void* d_out, int out_size, void* d_ws, size_t ws_size,
                              hipStream_t stream) {
    const float* x    = (const float*)d_in[0];
    const float* fwk  = (const float*)d_in[1];
    const float* fwrk = (const float*)d_in[2];
    const float* fwb  = (const float*)d_in[3];
    const float* bwk  = (const float*)d_in[4];
    const float* bwrk = (const float*)d_in[5];
    const float* bwb  = (const float*)d_in[6];
    float* out = (float*)d_out;

    const size_t seq = (size_t)NB * NT * NU;     // 26,214,400 elements
    float* buf_fw = (float*)d_ws;                // fw chain h (h0 then h1 in-place)
    float* buf_bw = buf_fw + seq;                // bw chain h
    int*   prog   = (int*)(buf_bw + seq);        // 256 per-chain progress counters

    // progress counters must be zero at every launch (deterministic replay)
    hipMemsetAsync(prog, 0, 2 * NGRP * sizeof(int), stream);

    lstm_scan<<<dim3(NGRP, 2, 2), 512, 0, stream>>>(
        x, fwk, fwrk, fwb, bwk, bwrk, bwb, buf_fw, buf_bw, prog);

    const int nvec = (int)(seq / 4);
    merge_out<<<2048, 256, 0, stream>>>(buf_fw, buf_bw, out, nvec);
}

// Round 11
// 1104.199 us; speedup vs baseline: 5.0719x; 5.0719x over previous
//
#include <hip/hip_runtime.h>
#include <cstdint>

typedef unsigned short u16;
typedef __attribute__((ext_vector_type(4))) float f32x4;
typedef __attribute__((ext_vector_type(8))) short bf16x8;   // 8 bf16 in 4 VGPRs
typedef __attribute__((ext_vector_type(4))) u16 u16x4;

constexpr int NB = 1024;   // batch
constexpr int NT = 200;    // time
constexpr int ND = 128;    // input dim
constexpr int NU = 128;    // units
constexpr int NG = 512;    // 4*U gates
constexpr int ROWS = 16;   // batch rows per block (MFMA M)
constexpr int NGRP = NB / ROWS;           // 64 groups
constexpr int CHUNK = 8;   // pipeline handshake granularity (divides NT)
constexpr int ABUF = ROWS * 512;          // 8192 u16 per A buffer
constexpr int LDS_A_ELEMS = 2 * ABUF;     // double-buffered: 32 KiB

__device__ __forceinline__ u16 f2bf(float x) {
    uint32_t u = __builtin_bit_cast(uint32_t, x);
    u = (u + 0x7fffu + ((u >> 16) & 1u)) >> 16;   // RNE
    return (u16)u;
}
__device__ __forceinline__ float bf2f(u16 b) {
    uint32_t u = ((uint32_t)b) << 16;
    return __builtin_bit_cast(float, u);
}
__device__ __forceinline__ float sigm(float x) {
    return __builtin_amdgcn_rcpf(1.f + __expf(-x));
}
__device__ __forceinline__ float tanh_fast(float x) {
    float e = __expf(-2.f * fabsf(x));
    float t = (1.f - e) * __builtin_amdgcn_rcpf(1.f + e);
    return copysignf(t, x);
}

// Poll RELAXED (no L2 inv) with a periodic acquire so cross-XCD progress is
// guaranteed; one final acquire = the synchronizes-with edge. r8 lesson:
// acquire EVERY poll = whole-L2 buffer_inv storm.
__device__ __forceinline__ void spin_gate(const int* p, int need) {
    int k = 0;
    while (__hip_atomic_load(p, __ATOMIC_RELAXED, __HIP_MEMORY_SCOPE_AGENT) < need) {
        __builtin_amdgcn_s_sleep(16);
        if ((++k & 63) == 0)
            (void)__hip_atomic_load(p, __ATOMIC_ACQUIRE, __HIP_MEMORY_SCOPE_AGENT);
    }
    (void)__hip_atomic_load(p, __ATOMIC_ACQUIRE, __HIP_MEMORY_SCOPE_AGENT);
}

// One LSTM layer scan for 16 batch rows. 3 register weight arrays (Wk_hi,
// Wr_hi, Wr_lo) — exactly 3 fit at 2 waves/SIMD (r6/r10: a 4th array or a
// 4-waves/SIMD launch bound forces global rematerialization, FETCH 25-60x).
// No Wk_lo (r10-validated: absmax 0.0112 < 0.0188). Double-buffered A tile ->
// ONE __syncthreads per step (step t reads buf p, writes h_t and x_{t+1} to
// p^1; no WAR within the step).
template<bool PROD, bool CONS>
__device__ __forceinline__ void run_layer(
    const float* __restrict__ Wk, const float* __restrict__ Wr,
    const float* __restrict__ Bv,
    const float* __restrict__ src, float* __restrict__ dst,
    u16* A, int* prog_c,
    const int dir, const int base_b,
    const int tid, const int q, const int cl, const int uu,
    const int sr, const int sc)
{
    // ---- resident weight fragments (B-side)
    bf16x8 wkh[4][4], wrh[4][4], wrl[4][4];
    #pragma unroll
    for (int g = 0; g < 4; ++g) {
        const int col = g * NU + uu;
        #pragma unroll
        for (int s = 0; s < 4; ++s) {
            bf16x8 fa, fh, fl;
            #pragma unroll
            for (int j = 0; j < 8; ++j) {
                const int k = s * 32 + q * 8 + j;
                fa[j] = (short)f2bf(Wk[k * NG + col]);
                const float w = Wr[k * NG + col];
                const u16 hi = f2bf(w);
                fh[j] = (short)hi;
                fl[j] = (short)f2bf(w - bf2f(hi));
            }
            wkh[g][s] = fa; wrh[g][s] = fh; wrl[g][s] = fl;
        }
    }
    float bias[4];
    #pragma unroll
    for (int g = 0; g < 4; ++g) bias[g] = Bv[g * NU + uu];

    for (int i = tid; i < LDS_A_ELEMS; i += 512) A[i] = 0;   // h planes start 0
    f32x4 cc = {0.f, 0.f, 0.f, 0.f};

    const size_t srow = (size_t)(base_b + sr) * (NT * NU) + sc;
    const uint32_t stg = (uint32_t)(sr * 1024 + ((2 * sc) ^ ((sr & 15) << 4))) >> 1;

    // consumer pre-gate: x_{t(0)},x_{t(1)} needed -> publish-grid-rounded 16
    if (CONS && tid == 0) spin_gate(prog_c, (2 * CHUNK < NT) ? 2 * CHUNK : NT);
    __syncthreads();   // zeroing ordered before staging (r4 lesson) + gate broadcast

    // prologue: stage x0 into buffer 0; prefetch x1
    {
        const float4 v = *(const float4*)&src[srow + (size_t)(dir ? NT - 1 : 0) * NU];
        const float vv[4] = {v.x, v.y, v.z, v.w};
        u16x4 hi4, lo4;
        #pragma unroll
        for (int e = 0; e < 4; ++e) {
            const u16 h = f2bf(vv[e]);
            hi4[e] = h;
            lo4[e] = f2bf(vv[e] - bf2f(h));
        }
        *(u16x4*)&A[stg]       = hi4;
        *(u16x4*)&A[stg + 128] = lo4;
    }
    float4 cur = *(const float4*)&src[srow + (size_t)(dir ? NT - 2 : 1) * NU];
    __syncthreads();   // x0 staged, visible

    int p = 0;
    for (int cs = 0; cs < NT; cs += CHUNK) {
        // gate chunk cs: prefetches up to x_{cs+9} -> need cs+16 (grid-rounded)
        if (CONS && cs > 0) {
            if (tid == 0) {
                const int need = (cs + 2 * CHUNK < NT) ? cs + 2 * CHUNK : NT;
                spin_gate(prog_c, need);
            }
            __syncthreads();
        }

        for (int step = cs; step < cs + CHUNK; ++step) {
            const int t = dir ? (NT - 1 - step) : step;
            const u16* Ard = A + p * ABUF;
            u16*       Awr = A + (p ^ 1) * ABUF;

            // ---- stage x_{t+1} (prefetched last step) into the NEXT buffer
            if (step + 1 < NT) {
                const float vv[4] = {cur.x, cur.y, cur.z, cur.w};
                u16x4 hi4, lo4;
                #pragma unroll
                for (int e = 0; e < 4; ++e) {
                    const u16 h = f2bf(vv[e]);
                    hi4[e] = h;
                    lo4[e] = f2bf(vv[e] - bf2f(h));
                }
                *(u16x4*)&Awr[stg]       = hi4;   // x_hi: k in [0,128)
                *(u16x4*)&Awr[stg + 128] = lo4;   // x_lo: k in [128,256)
            }
            // ---- prefetch x_{t+2} for next step's staging
            if (step + 2 < NT) {
                const int tf = dir ? (NT - 3 - step) : (step + 2);
                cur = *(const float4*)&src[srow + (size_t)tf * NU];
            }

            f32x4 accx[4], acch[4];   // x-side (carries bias) and h-side chains
            #pragma unroll
            for (int g = 0; g < 4; ++g) {
                accx[g] = (f32x4){bias[g], bias[g], bias[g], bias[g]};
                acch[g] = (f32x4){0.f, 0.f, 0.f, 0.f};
            }

            #pragma unroll
            for (int s = 0; s < 4; ++s) {
                const uint32_t ab =
                    (uint32_t)(cl * 1024 + ((s * 64 + q * 16) ^ ((cl & 15) << 4)));
                const bf16x8 axh = *(const bf16x8*)&Ard[(ab >> 1)];
                const bf16x8 axl = *(const bf16x8*)&Ard[(ab >> 1) + 128];
                const bf16x8 ahh = *(const bf16x8*)&Ard[(ab >> 1) + 256];
                const bf16x8 ahl = *(const bf16x8*)&Ard[(ab >> 1) + 384];
                #pragma unroll
                for (int g = 0; g < 4; ++g) {
                    accx[g] = __builtin_amdgcn_mfma_f32_16x16x32_bf16(axh, wkh[g][s], accx[g], 0, 0, 0);
                    accx[g] = __builtin_amdgcn_mfma_f32_16x16x32_bf16(axl, wkh[g][s], accx[g], 0, 0, 0);
                    acch[g] = __builtin_amdgcn_mfma_f32_16x16x32_bf16(ahh, wrh[g][s], acch[g], 0, 0, 0);
                    acch[g] = __builtin_amdgcn_mfma_f32_16x16x32_bf16(ahl, wrh[g][s], acch[g], 0, 0, 0);
                    acch[g] = __builtin_amdgcn_mfma_f32_16x16x32_bf16(ahh, wrl[g][s], acch[g], 0, 0, 0);
                }
            }

            // gates + state; C/D: col = lane&15 (unit), row = q*4+j (batch row)
            #pragma unroll
            for (int j = 0; j < 4; ++j) {
                const int r = q * 4 + j;
                const float gi = sigm(accx[0][j] + acch[0][j]);
                const float gf = sigm(accx[1][j] + acch[1][j]);
                const float gg = tanh_fast(accx[2][j] + acch[2][j]);
                const float go = sigm(accx[3][j] + acch[3][j]);
                const float cn = gf * cc[j] + gi * gg;
                cc[j] = cn;
                const float h = go * tanh_fast(cn);
                const u16 hh = f2bf(h);
                const u16 hl = f2bf(h - bf2f(hh));
                const uint32_t hb = (uint32_t)(r * 1024 + ((2 * uu) ^ ((r & 15) << 4)));
                Awr[(hb >> 1) + 256] = hh;   // h_hi plane of the NEXT buffer
                Awr[(hb >> 1) + 384] = hl;   // h_lo plane
                dst[(size_t)(base_b + r) * (NT * NU) + (size_t)t * NU + uu] = h;
            }

            __syncthreads();   // the ONLY per-step barrier: p-reads done,
                               // p^1 writes visible, dst stores drained
            // publish on the chunk grid: steps 0..step drained by the barrier
            if (PROD && tid == 0 && ((step + 1) & (CHUNK - 1)) == 0)
                __hip_atomic_store(prog_c, step + 1, __ATOMIC_RELEASE, __HIP_MEMORY_SCOPE_AGENT);
            p ^= 1;
        }
    }
}

// grid = (64 groups, 2 dirs, 2 layers) = 256 blocks = 1 per CU, all
// co-resident -> consumer spins cannot deadlock (producers never wait).
__global__ __launch_bounds__(512, 2)
void lstm_scan(const float* __restrict__ x,
               const float* __restrict__ fwk, const float* __restrict__ fwrk,
               const float* __restrict__ fwb,
               const float* __restrict__ bwk, const float* __restrict__ bwrk,
               const float* __restrict__ bwb,
               float* __restrict__ buf_fw, float* __restrict__ buf_bw,
               int* __restrict__ prog) {
    __shared__ __align__(16) u16 A[LDS_A_ELEMS];   // 2 x [16][512] bf16, swizzled

    const int tid   = threadIdx.x;
    const int lane  = tid & 63;
    const int wv    = tid >> 6;         // wave 0..7
    const int grp   = blockIdx.x;       // 0..63
    const int dir   = blockIdx.y;       // 0 = fw, 1 = bw
    const int layer = blockIdx.z;       // 0 = producer, 1 = consumer
    const int base_b = grp * ROWS;

    const float* kp = dir ? bwk  : fwk;
    const float* rp = dir ? bwrk : fwrk;
    const float* bp = dir ? bwb  : fwb;
    float* buf = dir ? buf_bw : buf_fw;
    int* prog_c = prog + dir * NGRP + grp;

    const int q  = lane >> 4;           // k-group 0..3
    const int cl = lane & 15;           // A-row / B-col within tile
    const int uu = (wv << 4) + cl;      // unit 0..127 owned by this lane

    const int sr = tid >> 5;            // staging row 0..15
    const int sc = (tid & 31) << 2;     // staging col 0..124

    if (layer == 0) {
        // layer 0: x -> buf (h0), publishing progress
        run_layer<true, false>(kp, rp, bp, x, buf, A, prog_c,
                               dir, base_b, tid, q, cl, uu, sr, sc);
    } else {
        // layer 1: buf (h0) -> buf in-place (h1), gated on producer progress.
        // In-place safe: h0[t] last read one step before h1[t] is written.
        run_layer<false, true>(kp + ND * NG, rp + NU * NG, bp + NG,
                               buf, buf, A, prog_c,
                               dir, base_b, tid, q, cl, uu, sr, sc);
    }
}

// ---- merge: out = 0.5*(fw + bw) ---------------------------------------------
__global__ void merge_out(const float* __restrict__ a, const float* __restrict__ b,
                          float* __restrict__ o, int nvec) {
    int i = blockIdx.x * blockDim.x + threadIdx.x;
    const int st = gridDim.x * blockDim.x;
    for (; i < nvec; i += st) {
        const float4 va = ((const float4*)a)[i];
        const float4 vb = ((const float4*)b)[i];
        float4 r;
        r.x = 0.5f * (va.x + vb.x);
        r.y = 0.5f * (va.y + vb.y);
        r.z = 0.5f * (va.z + vb.z);
        r.w = 0.5f * (va.w + vb.w);
        ((float4*)o)[i] = r;
    }
}

extern "C" void kernel_launch(void* const* d_in, const int* in_sizes, int n_in,
                              void* d_out, int out_size, void* d_ws, size_t ws_size,
                              hipStream_t stream) {
    const float* x    = (const float*)d_in[0];
    const float* fwk  = (const float*)d_in[1];
    const float* fwrk = (const float*)d_in[2];
    const float* fwb  = (const float*)d_in[3];
    const float* bwk  = (const float*)d_in[4];
    const float* bwrk = (const float*)d_in[5];
    const float* bwb  = (const float*)d_in[6];
    float* out = (float*)d_out;

    const size_t seq = (size_t)NB * NT * NU;     // 26,214,400 elements
    float* buf_fw = (float*)d_ws;                // fw chain h (h0 then h1 in-place)
    float* buf_bw = buf_fw + seq;                // bw chain h
    int*   prog   = (int*)(buf_bw + seq);        // per-chain progress counters

    // progress counters must be zero at every launch (deterministic replay)
    hipMemsetAsync(prog, 0, 2 * NGRP * sizeof(int), stream);

    lstm_scan<<<dim3(NGRP, 2, 2), 512, 0, stream>>>(
        x, fwk, fwrk, fwb, bwk, bwrk, bwb, buf_fw, buf_bw, prog);

    const int nvec = (int)(seq / 4);
    merge_out<<<2048, 256, 0, stream>>>(buf_fw, buf_bw, out, nvec);
}

// Round 12
// 1016.307 us; speedup vs baseline: 5.5105x; 1.0865x over previous
//
#include <hip/hip_runtime.h>
#include <cstdint>

typedef unsigned short u16;
typedef __attribute__((ext_vector_type(4))) float f32x4;
typedef __attribute__((ext_vector_type(8))) short bf16x8;   // 8 bf16 in 4 VGPRs
typedef __attribute__((ext_vector_type(4))) u16 u16x4;

constexpr int NB = 1024;   // batch
constexpr int NT = 200;    // time
constexpr int ND = 128;    // input dim
constexpr int NU = 128;    // units
constexpr int NG = 512;    // 4*U gates
constexpr int ROWS = 16;   // batch rows per block (MFMA M)
constexpr int NGRP = NB / ROWS;           // 64 groups
constexpr int CHUNK = 8;   // consumer gate granularity (divides NT)
constexpr int ABUF = ROWS * 512;          // 8192 u16 per A buffer
constexpr int LDS_A_ELEMS = 2 * ABUF;     // double-buffered: 32 KiB

__device__ __forceinline__ u16 f2bf(float x) {
    uint32_t u = __builtin_bit_cast(uint32_t, x);
    u = (u + 0x7fffu + ((u >> 16) & 1u)) >> 16;   // RNE
    return (u16)u;
}
__device__ __forceinline__ float bf2f(u16 b) {
    uint32_t u = ((uint32_t)b) << 16;
    return __builtin_bit_cast(float, u);
}
__device__ __forceinline__ float sigm(float x) {
    return __builtin_amdgcn_rcpf(1.f + __expf(-x));
}
__device__ __forceinline__ float tanh_fast(float x) {
    float e = __expf(-2.f * fabsf(x));
    float t = (1.f - e) * __builtin_amdgcn_rcpf(1.f + e);
    return copysignf(t, x);
}

// Poll RELAXED (no L2 inv) with a periodic acquire so cross-XCD progress is
// guaranteed; one final acquire (buffer_inv) = the synchronizes-with edge and
// flushes any stale prior-replay lines from this XCD's L2. r8 lesson: acquire
// EVERY poll = whole-L2 inv storm.
__device__ __forceinline__ void spin_gate(const int* p, int need) {
    int k = 0;
    while (__hip_atomic_load(p, __ATOMIC_RELAXED, __HIP_MEMORY_SCOPE_AGENT) < need) {
        __builtin_amdgcn_s_sleep(16);
        if ((++k & 63) == 0)
            (void)__hip_atomic_load(p, __ATOMIC_ACQUIRE, __HIP_MEMORY_SCOPE_AGENT);
    }
    (void)__hip_atomic_load(p, __ATOMIC_ACQUIRE, __HIP_MEMORY_SCOPE_AGENT);
}

// One LSTM layer scan for 16 batch rows. 3 register weight arrays (Wk_hi,
// Wr_hi, Wr_lo) — exactly 3 fit at 2 waves/SIMD (r6/r10: a 4th array or
// higher launch-bound occupancy forces global remat, FETCH 25-60x). No Wk_lo
// (r10: absmax 0.0112 < 0.0188). Double-buffered A -> ONE __syncthreads/step.
// r12: dst stores are RELAXED AGENT ATOMICS (sc0 sc1, write-through to the
// coherence point) and the publish is a RELAXED store after the barrier's
// vmcnt(0) drain -> NO buffer_wbl2 anywhere (r11 lesson: release-publish
// wbl2 every 8 steps x 16 producers/XCD = continuous L2 disruption).
template<bool PROD, bool CONS>
__device__ __forceinline__ void run_layer(
    const float* __restrict__ Wk, const float* __restrict__ Wr,
    const float* __restrict__ Bv,
    const float* __restrict__ src, float* __restrict__ dst,
    u16* A, int* prog_c,
    const int dir, const int base_b,
    const int tid, const int q, const int cl, const int uu,
    const int sr, const int sc)
{
    // ---- resident weight fragments (B-side)
    bf16x8 wkh[4][4], wrh[4][4], wrl[4][4];
    #pragma unroll
    for (int g = 0; g < 4; ++g) {
        const int col = g * NU + uu;
        #pragma unroll
        for (int s = 0; s < 4; ++s) {
            bf16x8 fa, fh, fl;
            #pragma unroll
            for (int j = 0; j < 8; ++j) {
                const int k = s * 32 + q * 8 + j;
                fa[j] = (short)f2bf(Wk[k * NG + col]);
                const float w = Wr[k * NG + col];
                const u16 hi = f2bf(w);
                fh[j] = (short)hi;
                fl[j] = (short)f2bf(w - bf2f(hi));
            }
            wkh[g][s] = fa; wrh[g][s] = fh; wrl[g][s] = fl;
        }
    }
    float bias[4];
    #pragma unroll
    for (int g = 0; g < 4; ++g) bias[g] = Bv[g * NU + uu];

    for (int i = tid; i < LDS_A_ELEMS; i += 512) A[i] = 0;   // h planes start 0
    f32x4 cc = {0.f, 0.f, 0.f, 0.f};

    const size_t srow = (size_t)(base_b + sr) * (NT * NU) + sc;
    const uint32_t stg = (uint32_t)(sr * 1024 + ((2 * sc) ^ ((sr & 15) << 4))) >> 1;

    // consumer pre-gate: chunk 0 reads up to x_{t(9)} -> need 10 (per-step pub)
    if (CONS && tid == 0) spin_gate(prog_c, (CHUNK + 2 < NT) ? CHUNK + 2 : NT);
    __syncthreads();   // zeroing ordered before staging (r4 lesson) + gate broadcast

    // prologue: stage x0 into buffer 0; prefetch x1
    {
        const float4 v = *(const float4*)&src[srow + (size_t)(dir ? NT - 1 : 0) * NU];
        const float vv[4] = {v.x, v.y, v.z, v.w};
        u16x4 hi4, lo4;
        #pragma unroll
        for (int e = 0; e < 4; ++e) {
            const u16 h = f2bf(vv[e]);
            hi4[e] = h;
            lo4[e] = f2bf(vv[e] - bf2f(h));
        }
        *(u16x4*)&A[stg]       = hi4;
        *(u16x4*)&A[stg + 128] = lo4;
    }
    float4 cur = *(const float4*)&src[srow + (size_t)(dir ? NT - 2 : 1) * NU];
    __syncthreads();   // x0 staged, visible

    int p = 0;
    for (int cs = 0; cs < NT; cs += CHUNK) {
        // gate chunk cs: prefetches up to x_{t(cs+9)} -> need cs+10
        if (CONS && cs > 0) {
            if (tid == 0) {
                const int need = (cs + CHUNK + 2 < NT) ? cs + CHUNK + 2 : NT;
                spin_gate(prog_c, need);
            }
            __syncthreads();
        }

        for (int step = cs; step < cs + CHUNK; ++step) {
            const int t = dir ? (NT - 1 - step) : step;
            const u16* Ard = A + p * ABUF;
            u16*       Awr = A + (p ^ 1) * ABUF;

            // ---- stage x_{t+1} (prefetched last step) into the NEXT buffer
            if (step + 1 < NT) {
                const float vv[4] = {cur.x, cur.y, cur.z, cur.w};
                u16x4 hi4, lo4;
                #pragma unroll
                for (int e = 0; e < 4; ++e) {
                    const u16 h = f2bf(vv[e]);
                    hi4[e] = h;
                    lo4[e] = f2bf(vv[e] - bf2f(h));
                }
                *(u16x4*)&Awr[stg]       = hi4;   // x_hi: k in [0,128)
                *(u16x4*)&Awr[stg + 128] = lo4;   // x_lo: k in [128,256)
            }
            // ---- prefetch x_{t+2} for next step's staging
            if (step + 2 < NT) {
                const int tf = dir ? (NT - 3 - step) : (step + 2);
                cur = *(const float4*)&src[srow + (size_t)tf * NU];
            }

            f32x4 accx[4], acch[4];   // x-side (carries bias) and h-side chains
            #pragma unroll
            for (int g = 0; g < 4; ++g) {
                accx[g] = (f32x4){bias[g], bias[g], bias[g], bias[g]};
                acch[g] = (f32x4){0.f, 0.f, 0.f, 0.f};
            }

            #pragma unroll
            for (int s = 0; s < 4; ++s) {
                const uint32_t ab =
                    (uint32_t)(cl * 1024 + ((s * 64 + q * 16) ^ ((cl & 15) << 4)));
                const bf16x8 axh = *(const bf16x8*)&Ard[(ab >> 1)];
                const bf16x8 axl = *(const bf16x8*)&Ard[(ab >> 1) + 128];
                const bf16x8 ahh = *(const bf16x8*)&Ard[(ab >> 1) + 256];
                const bf16x8 ahl = *(const bf16x8*)&Ard[(ab >> 1) + 384];
                #pragma unroll
                for (int g = 0; g < 4; ++g) {
                    accx[g] = __builtin_amdgcn_mfma_f32_16x16x32_bf16(axh, wkh[g][s], accx[g], 0, 0, 0);
                    accx[g] = __builtin_amdgcn_mfma_f32_16x16x32_bf16(axl, wkh[g][s], accx[g], 0, 0, 0);
                    acch[g] = __builtin_amdgcn_mfma_f32_16x16x32_bf16(ahh, wrh[g][s], acch[g], 0, 0, 0);
                    acch[g] = __builtin_amdgcn_mfma_f32_16x16x32_bf16(ahl, wrh[g][s], acch[g], 0, 0, 0);
                    acch[g] = __builtin_amdgcn_mfma_f32_16x16x32_bf16(ahh, wrl[g][s], acch[g], 0, 0, 0);
                }
            }

            // gates + state; C/D: col = lane&15 (unit), row = q*4+j (batch row)
            #pragma unroll
            for (int j = 0; j < 4; ++j) {
                const int r = q * 4 + j;
                const float gi = sigm(accx[0][j] + acch[0][j]);
                const float gf = sigm(accx[1][j] + acch[1][j]);
                const float gg = tanh_fast(accx[2][j] + acch[2][j]);
                const float go = sigm(accx[3][j] + acch[3][j]);
                const float cn = gf * cc[j] + gi * gg;
                cc[j] = cn;
                const float h = go * tanh_fast(cn);
                const u16 hh = f2bf(h);
                const u16 hl = f2bf(h - bf2f(hh));
                const uint32_t hb = (uint32_t)(r * 1024 + ((2 * uu) ^ ((r & 15) << 4)));
                Awr[(hb >> 1) + 256] = hh;   // h_hi plane of the NEXT buffer
                Awr[(hb >> 1) + 384] = hl;   // h_lo plane
                // coherent store (sc0 sc1): visible at the coherence point once
                // retired -> no wbl2 needed at publish time
                __hip_atomic_store(
                    &dst[(size_t)(base_b + r) * (NT * NU) + (size_t)t * NU + uu],
                    h, __ATOMIC_RELAXED, __HIP_MEMORY_SCOPE_AGENT);
            }

            __syncthreads();   // the ONLY per-step barrier: p-reads done,
                               // p^1 writes visible, vmcnt(0) drained
            // publish step+1 (steps 0..step retired at the coherence point).
            // Relaxed on purpose: ordering comes from the barrier's vmcnt(0).
            if (PROD && tid == 0) {
                asm volatile("s_waitcnt vmcnt(0)" ::: "memory");   // defensive no-op
                __hip_atomic_store(prog_c, step + 1, __ATOMIC_RELAXED,
                                   __HIP_MEMORY_SCOPE_AGENT);
            }
            p ^= 1;
        }
    }
}

// grid = (64 groups, 2 dirs, 2 layers) = 256 blocks = 1 per CU, all
// co-resident -> consumer spins cannot deadlock (producers never wait).
__global__ __launch_bounds__(512, 2)
void lstm_scan(const float* __restrict__ x,
               const float* __restrict__ fwk, const float* __restrict__ fwrk,
               const float* __restrict__ fwb,
               const float* __restrict__ bwk, const float* __restrict__ bwrk,
               const float* __restrict__ bwb,
               float* __restrict__ buf_fw, float* __restrict__ buf_bw,
               int* __restrict__ prog) {
    __shared__ __align__(16) u16 A[LDS_A_ELEMS];   // 2 x [16][512] bf16, swizzled

    const int tid   = threadIdx.x;
    const int lane  = tid & 63;
    const int wv    = tid >> 6;         // wave 0..7
    const int grp   = blockIdx.x;       // 0..63
    const int dir   = blockIdx.y;       // 0 = fw, 1 = bw
    const int layer = blockIdx.z;       // 0 = producer, 1 = consumer
    const int base_b = grp * ROWS;

    const float* kp = dir ? bwk  : fwk;
    const float* rp = dir ? bwrk : fwrk;
    const float* bp = dir ? bwb  : fwb;
    float* buf = dir ? buf_bw : buf_fw;
    int* prog_c = prog + dir * NGRP + grp;

    const int q  = lane >> 4;           // k-group 0..3
    const int cl = lane & 15;           // A-row / B-col within tile
    const int uu = (wv << 4) + cl;      // unit 0..127 owned by this lane

    const int sr = tid >> 5;            // staging row 0..15
    const int sc = (tid & 31) << 2;     // staging col 0..124

    if (layer == 0) {
        // layer 0: x -> buf (h0), publishing progress per step
        run_layer<true, false>(kp, rp, bp, x, buf, A, prog_c,
                               dir, base_b, tid, q, cl, uu, sr, sc);
    } else {
        // layer 1: buf (h0) -> buf in-place (h1), gated on producer progress.
        // In-place safe: h0[t] last read one step before h1[t] is written.
        run_layer<false, true>(kp + ND * NG, rp + NU * NG, bp + NG,
                               buf, buf, A, prog_c,
                               dir, base_b, tid, q, cl, uu, sr, sc);
    }
}

// ---- merge: out = 0.5*(fw + bw) ---------------------------------------------
__global__ void merge_out(const float* __restrict__ a, const float* __restrict__ b,
                          float* __restrict__ o, int nvec) {
    int i = blockIdx.x * blockDim.x + threadIdx.x;
    const int st = gridDim.x * blockDim.x;
    for (; i < nvec; i += st) {
        const float4 va = ((const float4*)a)[i];
        const float4 vb = ((const float4*)b)[i];
        float4 r;
        r.x = 0.5f * (va.x + vb.x);
        r.y = 0.5f * (va.y + vb.y);
        r.z = 0.5f * (va.z + vb.z);
        r.w = 0.5f * (va.w + vb.w);
        ((float4*)o)[i] = r;
    }
}

extern "C" void kernel_launch(void* const* d_in, const int* in_sizes, int n_in,
                              void* d_out, int out_size, void* d_ws, size_t ws_size,
                              hipStream_t stream) {
    const float* x    = (const float*)d_in[0];
    const float* fwk  = (const float*)d_in[1];
    const float* fwrk = (const float*)d_in[2];
    const float* fwb  = (const float*)d_in[3];
    const float* bwk  = (const float*)d_in[4];
    const float* bwrk = (const float*)d_in[5];
    const float* bwb  = (const float*)d_in[6];
    float* out = (float*)d_out;

    const size_t seq = (size_t)NB * NT * NU;     // 26,214,400 elements
    float* buf_fw = (float*)d_ws;                // fw chain h (h0 then h1 in-place)
    float* buf_bw = buf_fw + seq;                // bw chain h
    int*   prog   = (int*)(buf_bw + seq);        // per-chain progress counters

    // progress counters must be zero at every launch (deterministic replay)
    hipMemsetAsync(prog, 0, 2 * NGRP * sizeof(int), stream);

    lstm_scan<<<dim3(NGRP, 2, 2), 512, 0, stream>>>(
        x, fwk, fwrk, fwb, bwk, bwrk, bwb, buf_fw, buf_bw, prog);

    const int nvec = (int)(seq / 4);
    merge_out<<<2048, 256, 0, stream>>>(buf_fw, buf_bw, out, nvec);
}